// Round 3
// baseline (9908.810 us; speedup 1.0000x reference)
//
#include <hip/hip_runtime.h>

typedef unsigned short u16;
typedef unsigned int u32;
typedef unsigned long long u64;
typedef short short8 __attribute__((ext_vector_type(8)));
typedef float floatx4 __attribute__((ext_vector_type(4)));
typedef u32 u32x4 __attribute__((ext_vector_type(4)));

#define SLEN 2048
#define BATCH 64
#define FDIM 512
#define HDIM 512
#define NWG 128
#define NTH 320                        // 5 waves: wave0 recurrent, waves 1-4 x-proj (1 gate each)
#define GROUPS 4
#define ROWS 16                        // batch rows per group
#define HROW_U32 (HDIM/2)              // 256 u32 per h row
#define HGRP_U32 (ROWS*HROW_U32)       // 4096 u32 per group
#define HB_U32 (GROUPS*HGRP_U32)       // 16384 u32 per ring slot
#define NRING 4
#define WS_BYTES (NRING*HB_U32*4)      // 256 KiB h ring
#define SENT 0xFFFFFFFFu               // bf16 NaN-pair: unreachable for real h

#define LDS_W_U16 (4*16*64*8)          // 32768 u16 = 64 KiB per weight array
#define XR 20                          // padded row dim of scr_x tiles

// fp32 -> bf16 round-to-nearest-even
__device__ __forceinline__ u16 f2bf_rne(float f) {
  union { float f; u32 u; } v; v.f = f;
  u32 u = v.u + 0x7FFFu + ((v.u >> 16) & 1u);
  return (u16)(u >> 16);
}
__device__ __forceinline__ float sigmoidf_fast(float x) {
  return 1.0f / (1.0f + __expf(-x));
}
__device__ __forceinline__ float tanhf_fast(float x) {
  return 1.0f - 2.0f / (__expf(2.0f * x) + 1.0f);
}

// x-projection for one gate: A = x[16 rows][512] (per-lane row n), B from LDS frag order.
// Output 16x16 tile written col-major [col][row] into scr_x slot.
__device__ __forceinline__ void x_gemm1(
    const float* __restrict__ xrow, const u16* __restrict__ lds_wx,
    int gt, int lane, int n, int kq, float* __restrict__ sd)
{
  floatx4 a0 = {0.f, 0.f, 0.f, 0.f};
#pragma unroll
  for (int kk = 0; kk < 16; ++kk) {
    floatx4 xa = *(const floatx4*)(xrow + kk*32 + kq*8);
    floatx4 xb = *(const floatx4*)(xrow + kk*32 + kq*8 + 4);
    short8 ax;
#pragma unroll
    for (int j = 0; j < 4; ++j) {
      ax[j]     = (short)f2bf_rne(xa[j]);
      ax[4 + j] = (short)f2bf_rne(xb[j]);
    }
    short8 b0 = *(const short8*)&lds_wx[((gt*16 + kk)*64 + lane)*8];
    a0 = __builtin_amdgcn_mfma_f32_16x16x32_bf16(ax, b0, a0, 0, 0, 0);
  }
  *(floatx4*)(sd + ((size_t)gt*16 + n)*XR + kq*4) = a0;
}

#define HL(I, OFF) \
  asm volatile("global_load_dwordx4 %0, %1, off offset:" OFF " sc0 sc1" \
               : "=v"(hv[I]) : "v"(hp))

// Persistent grouped LSTM, sentinel-fused h exchange (no flags).
// WG (g = bid&3, c = bid>>2): batches [g*16,+16), h-cols [c*16,+16).
// wave0 step t: poll ring[t&3] data until no 0xFFFFFFFF word (16 coherent dwordx4,
// retry loop) -> reset own chunk of ring[(t-1)&3] to sentinel -> 64 MFMA (4 gates)
// -> gates/state in-register -> pack bf16 + store to ring[(t+1)&3]. Fire-and-forget.
// waves 1-4: x preacts for step t+2 (1 gate each) into 4-slot LDS ring.
__global__ __launch_bounds__(NTH, 1)
void lstm_persistent(
    const float* __restrict__ x,
    const float* __restrict__ w_ii, const float* __restrict__ b_ii,
    const float* __restrict__ w_hi, const float* __restrict__ b_hi,
    const float* __restrict__ w_if, const float* __restrict__ b_if,
    const float* __restrict__ w_hf, const float* __restrict__ b_hf,
    const float* __restrict__ w_ig, const float* __restrict__ b_ig,
    const float* __restrict__ w_hg, const float* __restrict__ b_hg,
    const float* __restrict__ w_io, const float* __restrict__ b_io,
    const float* __restrict__ w_ho, const float* __restrict__ b_ho,
    float* __restrict__ out, u32* __restrict__ hbuf)
{
  __shared__ __align__(16) u16 lds_wh[LDS_W_U16];        // 64 KiB
  __shared__ __align__(16) u16 lds_wx[LDS_W_U16];        // 64 KiB
  __shared__ __align__(16) float scr_x[4][4][16][XR];    // 20 KiB, 4-slot ring

  const int tid  = threadIdx.x;
  const int g    = blockIdx.x & 3;
  const int c    = blockIdx.x >> 2;
  const int wv   = tid >> 6;
  const int lane = tid & 63;
  const int n    = lane & 15;     // A-frag row (batch) AND D col (h-col)
  const int kq   = lane >> 4;

  // one-time weight pack fp32 -> bf16 frag order
  {
    const float* WH[4] = {w_hi, w_hf, w_hg, w_ho};
    const float* WX[4] = {w_ii, w_if, w_ig, w_io};
    for (int idx = tid; idx < 4*512*16; idx += NTH) {
      int col  = idx & 15;
      int k    = (idx >> 4) & 511;
      int gt   = idx >> 13;
      int kk   = k >> 5, rem = k & 31, quad = rem >> 3, j = rem & 7;
      int di   = ((gt*16 + kk)*64 + quad*16 + col)*8 + j;
      int src  = k*HDIM + c*16 + col;
      lds_wh[di] = f2bf_rne(WH[gt][src]);
      lds_wx[di] = f2bf_rne(WX[gt][src]);
    }
  }

  const int col = c*16 + n;
  const float bias0 = b_ii[col] + b_hi[col];
  const float bias1 = b_if[col] + b_hf[col];
  const float bias2 = b_ig[col] + b_hg[col];
  const float bias3 = b_io[col] + b_ho[col];
  floatx4 c_st = {0.f, 0.f, 0.f, 0.f};

  const float* xbase = x + (size_t)(g*ROWS + n) * (SLEN * FDIM);

  __syncthreads();   // weights ready

  // prologue: x preacts for t=0,1 into slots 0,1 (prefetch distance 2)
  if (wv >= 1) {
    x_gemm1(xbase,        lds_wx, wv - 1, lane, n, kq, &scr_x[0][0][0][0]);
    x_gemm1(xbase + FDIM, lds_wx, wv - 1, lane, n, kq, &scr_x[1][0][0][0]);
  }

  for (int t = 0; t < SLEN; ++t) {
    __syncthreads();   // scr_x slot handoff (one barrier per step)

    if (wv >= 1) {
      if (t + 2 < SLEN)
        x_gemm1(xbase + (size_t)(t + 2)*FDIM, lds_wx, wv - 1, lane, n, kq,
                &scr_x[(t + 2) & 3][0][0][0]);
    } else {
      const float* sx = &scr_x[t & 3][0][0][0];
      floatx4 sxv0 = *(const floatx4*)(sx + (0*16 + n)*XR + kq*4);
      floatx4 sxv1 = *(const floatx4*)(sx + (1*16 + n)*XR + kq*4);
      floatx4 sxv2 = *(const floatx4*)(sx + (2*16 + n)*XR + kq*4);
      floatx4 sxv3 = *(const floatx4*)(sx + (3*16 + n)*XR + kq*4);

      floatx4 acc0 = {0.f,0.f,0.f,0.f}, acc1 = {0.f,0.f,0.f,0.f};
      floatx4 acc2 = {0.f,0.f,0.f,0.f}, acc3 = {0.f,0.f,0.f,0.f};

      if (t > 0) {
        // --- data-poll: h row n, quarter kq, 16 coherent 16B loads, retry on sentinel ---
        const u32* hp = hbuf + (size_t)(t & 3)*HB_U32 + g*HGRP_U32 + n*HROW_U32 + kq*4;
        u32x4 hv[16];
        int ready;
        do {
          HL(0,"0");   HL(1,"64");  HL(2,"128"); HL(3,"192");
          HL(4,"256"); HL(5,"320"); HL(6,"384"); HL(7,"448");
          HL(8,"512"); HL(9,"576"); HL(10,"640"); HL(11,"704");
          HL(12,"768"); HL(13,"832"); HL(14,"896"); HL(15,"960");
          asm volatile("s_waitcnt vmcnt(0)" ::: "memory");
          __builtin_amdgcn_sched_barrier(0);
          u32 mx = 0u;
#pragma unroll
          for (int i = 0; i < 16; ++i) {
#pragma unroll
            for (int j = 0; j < 4; ++j) {
              u32 w = hv[i][j];
              mx = (w > mx) ? w : mx;     // any sentinel -> mx == SENT
            }
          }
          ready = __all((int)(mx != SENT));
        } while (!ready);

        // --- re-arm: reset own 16x16 chunk of ring[(t-1)&3] (next polled at t+3) ---
        {
          u32* rz = hbuf + (size_t)((t - 1) & 3)*HB_U32 + g*HGRP_U32;
          int i0 = lane, i1 = lane + 64;   // 128 words, 2 per lane
          __hip_atomic_store(&rz[(i0 >> 3)*HROW_U32 + c*8 + (i0 & 7)], SENT,
                             __ATOMIC_RELAXED, __HIP_MEMORY_SCOPE_AGENT);
          __hip_atomic_store(&rz[(i1 >> 3)*HROW_U32 + c*8 + (i1 & 7)], SENT,
                             __ATOMIC_RELAXED, __HIP_MEMORY_SCOPE_AGENT);
        }

        // --- recurrent MFMA: data already in registers ---
#pragma unroll
        for (int kk = 0; kk < 16; ++kk) {
          union { u32x4 u; short8 s; } ha; ha.u = hv[kk];
          acc0 = __builtin_amdgcn_mfma_f32_16x16x32_bf16(ha.s, *(const short8*)&lds_wh[((0*16+kk)*64+lane)*8], acc0, 0,0,0);
          acc1 = __builtin_amdgcn_mfma_f32_16x16x32_bf16(ha.s, *(const short8*)&lds_wh[((1*16+kk)*64+lane)*8], acc1, 0,0,0);
          acc2 = __builtin_amdgcn_mfma_f32_16x16x32_bf16(ha.s, *(const short8*)&lds_wh[((2*16+kk)*64+lane)*8], acc2, 0,0,0);
          acc3 = __builtin_amdgcn_mfma_f32_16x16x32_bf16(ha.s, *(const short8*)&lds_wh[((3*16+kk)*64+lane)*8], acc3, 0,0,0);
        }
      }

      // gates + state, in-register (lane: batch rows kq*4+r, h-col n)
      float hnew[4];
#pragma unroll
      for (int r = 0; r < 4; ++r) {
        float gi = sigmoidf_fast(acc0[r] + sxv0[r] + bias0);
        float gf = sigmoidf_fast(acc1[r] + sxv1[r] + bias1);
        float gg = tanhf_fast  (acc2[r] + sxv2[r] + bias2);
        float go = sigmoidf_fast(acc3[r] + sxv3[r] + bias3);
        c_st[r] = gf * c_st[r] + gi * gg;
        hnew[r] = go * tanhf_fast(c_st[r]);
      }

      if (t == SLEN - 1) {
#pragma unroll
        for (int r = 0; r < 4; ++r) {
          int row = g*ROWS + kq*4 + r;
          out[row*HDIM + col]              = hnew[r];   // h
          out[BATCH*HDIM + row*HDIM + col] = c_st[r];   // c
        }
      } else {
        // pack bf16 pairs and fire-and-forget into ring[(t+1)&3]; arrival IS the signal
        u32 hb[4];
#pragma unroll
        for (int r = 0; r < 4; ++r) hb[r] = (u32)f2bf_rne(hnew[r]);
        u32* hdst = hbuf + (size_t)((t + 1) & 3)*HB_U32 + g*HGRP_U32;
#pragma unroll
        for (int r = 0; r < 4; ++r) {
          u32 o = (u32)__shfl_xor((int)hb[r], 1);   // partner col n^1
          if ((n & 1) == 0) {
            u32 val = (o << 16) | hb[r];            // low u16 = even col
            __hip_atomic_store(&hdst[(kq*4 + r)*HROW_U32 + c*8 + (n >> 1)],
                               val, __ATOMIC_RELAXED, __HIP_MEMORY_SCOPE_AGENT);
          }
        }
      }
    }
  }
}

extern "C" void kernel_launch(void* const* d_in, const int* in_sizes, int n_in,
                              void* d_out, int out_size, void* d_ws, size_t ws_size,
                              hipStream_t stream) {
  // ws: 4-ring h buffer (u32-packed bf16, [ring][group][row][256]) -- sentinel-armed
  u32* hbuf = (u32*)d_ws;
  (void)hipMemsetAsync(d_ws, 0xFF, WS_BYTES, stream);   // all rings -> sentinel

  lstm_persistent<<<dim3(NWG), dim3(NTH), 0, stream>>>(
      (const float*)d_in[0],
      (const float*)d_in[1],  (const float*)d_in[2],   // w_ii, b_ii
      (const float*)d_in[3],  (const float*)d_in[4],   // w_hi, b_hi
      (const float*)d_in[5],  (const float*)d_in[6],   // w_if_, b_if_
      (const float*)d_in[7],  (const float*)d_in[8],   // w_hf, b_hf
      (const float*)d_in[9],  (const float*)d_in[10],  // w_ig, b_ig
      (const float*)d_in[11], (const float*)d_in[12],  // w_hg, b_hg
      (const float*)d_in[13], (const float*)d_in[14],  // w_io, b_io
      (const float*)d_in[15], (const float*)d_in[16],  // w_ho, b_ho
      (float*)d_out, hbuf);
}